// Round 1
// 744.487 us; speedup vs baseline: 1.1056x; 1.1056x over previous
//
#include <hip/hip_runtime.h>

// ---------------------------------------------------------------- constants
#define H_   32
#define D_   128
#define HID_ 4096
#define B_   4
#define S_   1024
#define T_   4096
#define NSLOTS_ 16384
#define NQKV_ 4352   // HID + 2*D

typedef __attribute__((ext_vector_type(8))) __bf16 bf16x8;
typedef __attribute__((ext_vector_type(4))) __bf16 bf16x4;
typedef __attribute__((ext_vector_type(4))) float  f32x4;

// async global->LDS, 16B per lane; lds dest = wave-uniform base + lane*16
__device__ __forceinline__ void gld_lds16(const __bf16* g, __bf16* l)
{
    __builtin_amdgcn_global_load_lds(
        (const __attribute__((address_space(1))) void*)g,
        (__attribute__((address_space(3))) void*)l, 16, 0, 0);
}

// ---------------------------------------------------------------- cast fp32 -> bf16 (vectorized)
__global__ __launch_bounds__(256) void cast_bf16_kernel(
    const float* __restrict__ in, __bf16* __restrict__ out, int n4)
{
    int i = blockIdx.x * 256 + threadIdx.x;
    if (i < n4) {
        f32x4 v = ((const f32x4*)in)[i];
        bf16x4 o;
        o[0] = (__bf16)v[0]; o[1] = (__bf16)v[1];
        o[2] = (__bf16)v[2]; o[3] = (__bf16)v[3];
        ((bf16x4*)out)[i] = o;
    }
}

// ---------------------------------------------------------------- transpose + cast: in (R x C) f32 -> out (C x R) bf16
__global__ __launch_bounds__(256) void transpose_cast_kernel(
    const float* __restrict__ in, __bf16* __restrict__ out, int R, int C)
{
    __shared__ float tile[32][33];
    int c0 = blockIdx.x * 32, r0 = blockIdx.y * 32;
    int tx = threadIdx.x;   // 0..31
    int ty = threadIdx.y;   // 0..7
#pragma unroll
    for (int j = 0; j < 32; j += 8)
        tile[ty + j][tx] = in[(size_t)(r0 + ty + j) * C + c0 + tx];
    __syncthreads();
#pragma unroll
    for (int j = 0; j < 32; j += 8)
        out[(size_t)(c0 + ty + j) * R + r0 + tx] = (__bf16)tile[tx][ty + j];
}

// ---------------------------------------------------------------- 256x256 8-phase bf16 GEMM (m201 structure)
// C(MxN, f32) = A(MxK) * Bt(NxK)^T + bias(N).
// 512 thr = 8 waves (2M x 4N); per-wave 128x64 out; BK=64 as 2 kk-halves.
// LDS: 2 dbuf x {A_kk0,A_kk1,B_kk0,B_kk1} x 16KB = 128KB.
// Swizzle: physical 16B block = logical ^ ((row>>1)&3) (involution),
// applied via pre-swizzled global SOURCE on staging + swizzled ds_read.
// Stage stream item idx: j=idx>>2 (K-tile), sel=idx&3 in order
// [B_kk0, B_kk1, A_kk0, A_kk1]; during K-tile k we stage items 4k+7..4k+10
// (= A_kk1(k+1), B_kk0(k+2), B_kk1(k+2), A_kk0(k+2)) which are always
// dead regions: B dead after phase0, A_kk0 after phase1, A_kk1 other buf.
// vmcnt(6) once per K-tile (3 half-tiles in flight), vmcnt(0) only to drain.

#define SB()    __builtin_amdgcn_sched_barrier(0)
#define BAR()   __builtin_amdgcn_s_barrier()
#define LGKM0() asm volatile("s_waitcnt lgkmcnt(0)" ::: "memory")

#define LOAD_A(MH, KK)                                                          \
    _Pragma("unroll")                                                           \
    for (int m = 0; m < 4; ++m)                                                 \
        afr[m] = *(const bf16x8*)&lds[buf][KK][(wm * 128 + ((MH)*4 + m) * 16 + col) * 32 + pbE];

#define MFMA_QUAD(MH, KK)                                                       \
    __builtin_amdgcn_s_setprio(1);                                              \
    _Pragma("unroll")                                                           \
    for (int m = 0; m < 4; ++m) {                                               \
        _Pragma("unroll")                                                       \
        for (int n = 0; n < 4; ++n)                                             \
            acc[(MH)*4 + m][n] = __builtin_amdgcn_mfma_f32_16x16x32_bf16(       \
                afr[m], bfr[KK][n], acc[(MH)*4 + m][n], 0, 0, 0);               \
    }                                                                           \
    __builtin_amdgcn_s_setprio(0);

__global__ __launch_bounds__(512, 2) void gemm256_kernel(
    const __bf16* __restrict__ A, const __bf16* __restrict__ Bt,
    const float* __restrict__ bias, float* __restrict__ C,
    int M, int N, int K)
{
    // region: 0=A_kk0, 1=A_kk1, 2=B_kk0, 3=B_kk1 (each 256 rows x 32 cols)
    __shared__ __bf16 lds[2][4][8192];

    const int tid  = threadIdx.x;
    const int lane = tid & 63;
    const int wave = tid >> 6;          // 0..7
    const int wm   = wave >> 2;         // 0..1
    const int wn   = wave & 3;          // 0..3
    const int col  = lane & 15;
    const int quad = lane >> 4;
    const int pbE  = (quad ^ ((lane >> 1) & 3)) * 8;   // swizzled block, elems
    const int bm   = blockIdx.y * 256;
    const int bn   = blockIdx.x * 256;
    const int nk   = K >> 6;
    const int nitems = nk << 2;

    // staging: per wave-instruction 64 lanes x 16B = 16 rows x 64B.
    // lane covers physical block (lane&3) of row (lane>>2); its logical
    // (= global) block is (lane&3) ^ ((lane>>3)&3)  [same involution].
    const int sR = wave * 32 + (lane >> 2);
    const int sb = ((lane & 3) ^ ((lane >> 3) & 3)) * 8;
    const __bf16* gA = A  + (size_t)(bm + sR) * K + sb;
    const __bf16* gB = Bt + (size_t)(bn + sR) * K + sb;

    f32x4 acc[8][4];
#pragma unroll
    for (int m = 0; m < 8; ++m)
#pragma unroll
        for (int n = 0; n < 4; ++n)
#pragma unroll
            for (int r = 0; r < 4; ++r) acc[m][n][r] = 0.f;

    auto stage = [&](int idx) {
        if (idx >= nitems) return;
        const int j   = idx >> 2;
        const int sel = idx & 3;
        const int reg = sel ^ 2;        // 0,1 -> B regions 2,3 ; 2,3 -> A 0,1
        const __bf16* g = (sel & 2) ? gA : gB;
        const size_t koff = (size_t)j * 64 + (size_t)(sel & 1) * 32;
        __bf16* l = &lds[j & 1][reg][wave * 1024];
        gld_lds16(g + koff, l);
        gld_lds16(g + koff + (size_t)16 * K, l + 512);
    };

    // prologue: items 0..6 (K-tile0 complete + 3 of K-tile1)
    stage(0); stage(1); stage(2); stage(3);
    asm volatile("s_waitcnt vmcnt(4)" ::: "memory");
    stage(4); stage(5); stage(6);
    asm volatile("s_waitcnt vmcnt(6)" ::: "memory");
    BAR();
    SB();

    for (int k = 0; k < nk; ++k) {
        const int buf = k & 1;
        bf16x8 bfr[2][4];
        bf16x8 afr[4];

        // -------- phase 0: all B (8) + A m0-3 kk0 (4); MFMA m0-3 kk0
#pragma unroll
        for (int kk = 0; kk < 2; ++kk)
#pragma unroll
            for (int n = 0; n < 4; ++n)
                bfr[kk][n] = *(const bf16x8*)&lds[buf][2 + kk][(wn * 64 + n * 16 + col) * 32 + pbE];
        LOAD_A(0, 0)
        stage(4 * k + 7);
        SB(); BAR(); LGKM0(); SB();
        MFMA_QUAD(0, 0)
        SB(); BAR(); SB();

        // -------- phase 1: A m4-7 kk0; MFMA m4-7 kk0
        LOAD_A(1, 0)
        stage(4 * k + 8);
        SB(); BAR(); LGKM0(); SB();
        MFMA_QUAD(1, 0)
        SB(); BAR(); SB();

        // -------- phase 2: A m0-3 kk1; MFMA m0-3 kk1
        LOAD_A(0, 1)
        stage(4 * k + 9);
        SB(); BAR(); LGKM0(); SB();
        MFMA_QUAD(0, 1)
        SB(); BAR(); SB();

        // -------- phase 3: A m4-7 kk1; MFMA m4-7 kk1; counted vmcnt
        LOAD_A(1, 1)
        stage(4 * k + 10);
        SB(); BAR(); LGKM0(); SB();
        MFMA_QUAD(1, 1)
        SB();
        if (k < nk - 2) asm volatile("s_waitcnt vmcnt(6)" ::: "memory");
        else            asm volatile("s_waitcnt vmcnt(0)" ::: "memory");
        BAR();
        SB();
    }

    // epilogue: D row = quad*4+r, col = lane&15 within each 16x16 frag
#pragma unroll
    for (int m = 0; m < 8; ++m) {
#pragma unroll
        for (int n = 0; n < 4; ++n) {
            const int r0 = bm + wm * 128 + m * 16 + quad * 4;
            const int c0 = bn + wn * 64 + n * 16 + col;
            const float bv = bias[c0];
#pragma unroll
            for (int r = 0; r < 4; ++r)
                C[(size_t)(r0 + r) * N + c0] = acc[m][n][r] + bv;
        }
    }
}

// ---------------------------------------------------------------- RoPE + cache scatter + bf16 q/k/v
__global__ __launch_bounds__(256) void rope_scatter_kernel(
    const float* __restrict__ qkv, const float* __restrict__ cosb,
    const float* __restrict__ sinb, const int* __restrict__ slots,
    __bf16* __restrict__ q16, __bf16* __restrict__ k16, __bf16* __restrict__ v16,
    float* __restrict__ kcache, float* __restrict__ vcache)
{
    const int t = blockIdx.x;
    const int tid = threadIdx.x;
    const float* row = qkv + (size_t)t * NQKV_;
    const float* cr = cosb + (size_t)t * 64;
    const float* sr = sinb + (size_t)t * 64;
    const int slot = slots[t];

#pragma unroll
    for (int i = 0; i < 8; ++i) {
        int p = tid + 256 * i;       // 0..2047
        int h = p >> 6;
        int d = p & 63;
        float x1 = row[h * 128 + d];
        float x2 = row[h * 128 + 64 + d];
        float c = cr[d], s = sr[d];
        q16[(size_t)t * HID_ + h * 128 + d]      = (__bf16)(x1 * c - x2 * s);
        q16[(size_t)t * HID_ + h * 128 + 64 + d] = (__bf16)(x2 * c + x1 * s);
    }
    if (tid < 64) {
        int d = tid;
        float x1 = row[HID_ + d];
        float x2 = row[HID_ + 64 + d];
        float c = cr[d], s = sr[d];
        float o1 = x1 * c - x2 * s;
        float o2 = x2 * c + x1 * s;
        kcache[(size_t)slot * D_ + d]      = o1;
        kcache[(size_t)slot * D_ + 64 + d] = o2;
        k16[(size_t)t * D_ + d]      = (__bf16)o1;
        k16[(size_t)t * D_ + 64 + d] = (__bf16)o2;
    }
    if (tid < 128) {
        float v = row[HID_ + 128 + tid];
        vcache[(size_t)slot * D_ + tid] = v;
        v16[(size_t)t * D_ + tid] = (__bf16)v;
    }
}

// ---------------------------------------------------------------- flash MQA attention (bf16 MFMA)
// grid (4, H, B): block processes q-tiles qt=blockIdx.x AND 7-blockIdx.x
// (uniform 18 k-steps/block -> no causal tail imbalance).
__global__ __launch_bounds__(256) void attn_kernel(
    const __bf16* __restrict__ Q, const __bf16* __restrict__ Kc,
    const __bf16* __restrict__ Vc, __bf16* __restrict__ O)
{
    __shared__ __bf16 sK[64][136];      // k-tile (s x d) row-major
    __shared__ __bf16 sVt[128][72];     // V transposed (d x s)
    __shared__ __bf16 sP[4][32][72];    // per-wave P round-trip (C-layout -> A-layout)

    const int h  = blockIdx.y;
    const int b  = blockIdx.z;
    const int tid = threadIdx.x, lane = tid & 63, wave = tid >> 6;
    const int col = lane & 15, quad = lane >> 4;
    const int tbase = b * S_;
    const float scale = 0.08838834764831845f; // 1/sqrt(128)

    for (int half = 0; half < 2; ++half) {
        const int qt = half ? (7 - blockIdx.x) : blockIdx.x;
        const int qb = qt * 128;

        bf16x8 aq[2][4];
#pragma unroll
        for (int mt = 0; mt < 2; ++mt)
#pragma unroll
            for (int ks = 0; ks < 4; ++ks)
                aq[mt][ks] = *(const bf16x8*)&Q[(size_t)(tbase + qb + wave * 32 + mt * 16 + col) * HID_
                                                + h * 128 + ks * 32 + quad * 8];

        f32x4 o[2][8];
#pragma unroll
        for (int mt = 0; mt < 2; ++mt)
#pragma unroll
            for (int nd = 0; nd < 8; ++nd)
#pragma unroll
                for (int r = 0; r < 4; ++r) o[mt][nd][r] = 0.f;
        float m_i[2][4], l_i[2][4];
#pragma unroll
        for (int mt = 0; mt < 2; ++mt)
#pragma unroll
            for (int r = 0; r < 4; ++r) { m_i[mt][r] = -3.0e38f; l_i[mt][r] = 0.f; }

        const int ntiles = qt * 2 + 2;
        for (int kt = 0; kt < ntiles; ++kt) {
            const int kb = kt * 64;
            __syncthreads();
            // stage K (64 x 128) row-major, coalesced vector loads
#pragma unroll
            for (int i = 0; i < 4; ++i) {
                int c = tid + i * 256;           // 0..1023
                int srow = c >> 4;               // 0..63
                int d0 = (c & 15) * 8;
                *(uint4*)&sK[srow][d0] = *(const uint4*)&Kc[(size_t)(tbase + kb + srow) * D_ + d0];
            }
            // stage V transposed: srow = c&63 so consecutive lanes write
            // consecutive sVt elements (2-way bank alias = free; was 16-way)
#pragma unroll
            for (int i = 0; i < 4; ++i) {
                int c = tid + i * 256;
                int srow = c & 63;
                int d0 = (c >> 6) * 8;
                bf16x8 v = *(const bf16x8*)&Vc[(size_t)(tbase + kb + srow) * D_ + d0];
#pragma unroll
                for (int j = 0; j < 8; ++j) sVt[d0 + j][srow] = v[j];
            }
            __syncthreads();

            // QK^T: per wave 32x64 scores
            f32x4 sc[2][4];
#pragma unroll
            for (int mt = 0; mt < 2; ++mt)
#pragma unroll
                for (int nt = 0; nt < 4; ++nt)
#pragma unroll
                    for (int r = 0; r < 4; ++r) sc[mt][nt][r] = 0.f;
#pragma unroll
            for (int ks = 0; ks < 4; ++ks) {
                bf16x8 bk[4];
#pragma unroll
                for (int nt = 0; nt < 4; ++nt)
                    bk[nt] = *(const bf16x8*)&sK[nt * 16 + col][ks * 32 + quad * 8];
#pragma unroll
                for (int mt = 0; mt < 2; ++mt)
#pragma unroll
                    for (int nt = 0; nt < 4; ++nt)
                        sc[mt][nt] = __builtin_amdgcn_mfma_f32_16x16x32_bf16(
                            aq[mt][ks], bk[nt], sc[mt][nt], 0, 0, 0);
            }

            // scale + causal mask + online softmax
#pragma unroll
            for (int mt = 0; mt < 2; ++mt) {
#pragma unroll
                for (int r = 0; r < 4; ++r) {
                    int qrow = qb + wave * 32 + mt * 16 + quad * 4 + r;
#pragma unroll
                    for (int nt = 0; nt < 4; ++nt) {
                        float v = sc[mt][nt][r] * scale;
                        int kcol = kb + nt * 16 + col;
                        sc[mt][nt][r] = (kcol > qrow) ? -3.0e38f : v;
                    }
                    float mx = sc[mt][0][r];
#pragma unroll
                    for (int nt = 1; nt < 4; ++nt) mx = fmaxf(mx, sc[mt][nt][r]);
#pragma unroll
                    for (int x = 1; x < 16; x <<= 1) mx = fmaxf(mx, __shfl_xor(mx, x, 64));
                    float mnew = fmaxf(m_i[mt][r], mx);
                    float alpha = __expf(m_i[mt][r] - mnew);
                    m_i[mt][r] = mnew;
                    float rs = 0.f;
#pragma unroll
                    for (int nt = 0; nt < 4; ++nt) {
                        float p = __expf(sc[mt][nt][r] - mnew);
                        sc[mt][nt][r] = p;
                        rs += p;
                    }
#pragma unroll
                    for (int x = 1; x < 16; x <<= 1) rs += __shfl_xor(rs, x, 64);
                    l_i[mt][r] = l_i[mt][r] * alpha + rs;
#pragma unroll
                    for (int nd = 0; nd < 8; ++nd) o[mt][nd][r] *= alpha;
                }
            }

            // P: C-layout regs -> per-wave LDS; same-wave RAW needs NO barrier
#pragma unroll
            for (int mt = 0; mt < 2; ++mt)
#pragma unroll
                for (int nt = 0; nt < 4; ++nt)
#pragma unroll
                    for (int r = 0; r < 4; ++r)
                        sP[wave][mt * 16 + quad * 4 + r][nt * 16 + col] = (__bf16)sc[mt][nt][r];

            // PV: O(32 x 128) += P(32 x 64) * V(64 x 128)
#pragma unroll
            for (int ks2 = 0; ks2 < 2; ++ks2) {
                bf16x8 ap[2];
#pragma unroll
                for (int mt = 0; mt < 2; ++mt)
                    ap[mt] = *(const bf16x8*)&sP[wave][mt * 16 + col][ks2 * 32 + quad * 8];
#pragma unroll
                for (int nd = 0; nd < 8; ++nd) {
                    bf16x8 bv = *(const bf16x8*)&sVt[nd * 16 + col][ks2 * 32 + quad * 8];
#pragma unroll
                    for (int mt = 0; mt < 2; ++mt)
                        o[mt][nd] = __builtin_amdgcn_mfma_f32_16x16x32_bf16(
                            ap[mt], bv, o[mt][nd], 0, 0, 0);
                }
            }
        }

        // epilogue: O /= l, write bf16 (T, HID)
#pragma unroll
        for (int mt = 0; mt < 2; ++mt) {
#pragma unroll
            for (int r = 0; r < 4; ++r) {
                int t = tbase + qb + wave * 32 + mt * 16 + quad * 4 + r;
                float inv_l = 1.f / l_i[mt][r];
#pragma unroll
                for (int nd = 0; nd < 8; ++nd)
                    O[(size_t)t * HID_ + h * 128 + nd * 16 + col] = (__bf16)(o[mt][nd][r] * inv_l);
            }
        }
    }
}

// ---------------------------------------------------------------- launch
extern "C" void kernel_launch(void* const* d_in, const int* in_sizes, int n_in,
                              void* d_out, int out_size, void* d_ws, size_t ws_size,
                              hipStream_t stream)
{
    const float* hidden  = (const float*)d_in[0];
    const float* cosb    = (const float*)d_in[1];
    const float* sinb    = (const float*)d_in[2];
    const float* kc_in   = (const float*)d_in[3];
    const float* vc_in   = (const float*)d_in[4];
    const float* qkv_w   = (const float*)d_in[5];
    const float* qkv_b   = (const float*)d_in[6];
    const float* dense_w = (const float*)d_in[7];
    const float* dense_b = (const float*)d_in[8];
    const int*   slots   = (const int*)d_in[9];

    float* out    = (float*)d_out;
    float* kc_out = out + (size_t)T_ * HID_;
    float* vc_out = kc_out + (size_t)NSLOTS_ * D_;

    char* ws = (char*)d_ws;
    __bf16* A16 = (__bf16*)(ws);
    __bf16* W1T = (__bf16*)(ws + 33554432);
    float*  QKV = (float*)(ws + 69206016);
    __bf16* W2T = (__bf16*)(ws + 69206016);   // alias: qkv f32 dead after rope
    __bf16* Q16 = (__bf16*)d_out;             // staged in out region (dead before GEMM2)
    __bf16* K16 = (__bf16*)((char*)d_out + 33554432);
    __bf16* V16 = (__bf16*)((char*)d_out + 34603008);

    cast_bf16_kernel<<<(T_ * HID_ / 4 + 255) / 256, 256, 0, stream>>>(hidden, A16, T_ * HID_ / 4);
    transpose_cast_kernel<<<dim3(NQKV_ / 32, HID_ / 32), dim3(32, 8), 0, stream>>>(qkv_w, W1T, HID_, NQKV_);
    gemm256_kernel<<<dim3(NQKV_ / 256, T_ / 256), 512, 0, stream>>>(A16, W1T, qkv_b, QKV, T_, NQKV_, HID_);
    hipMemcpyAsync(kc_out, kc_in, (size_t)NSLOTS_ * D_ * 4, hipMemcpyDeviceToDevice, stream);
    hipMemcpyAsync(vc_out, vc_in, (size_t)NSLOTS_ * D_ * 4, hipMemcpyDeviceToDevice, stream);
    rope_scatter_kernel<<<T_, 256, 0, stream>>>(QKV, cosb, sinb, slots, Q16, K16, V16, kc_out, vc_out);
    transpose_cast_kernel<<<dim3(HID_ / 32, HID_ / 32), dim3(32, 8), 0, stream>>>(dense_w, W2T, HID_, HID_);
    attn_kernel<<<dim3(4, H_, B_), 256, 0, stream>>>(Q16, K16, V16, A16);
    gemm256_kernel<<<dim3(HID_ / 256, T_ / 256), 512, 0, stream>>>(A16, W2T, dense_b, out, T_, HID_, HID_);
}

// Round 2
// 734.412 us; speedup vs baseline: 1.1208x; 1.0137x over previous
//
#include <hip/hip_runtime.h>

// ---------------------------------------------------------------- constants
#define H_   32
#define D_   128
#define HID_ 4096
#define B_   4
#define S_   1024
#define T_   4096
#define NSLOTS_ 16384
#define NQKV_ 4352   // HID + 2*D

typedef __attribute__((ext_vector_type(8))) __bf16 bf16x8;
typedef __attribute__((ext_vector_type(4))) __bf16 bf16x4;
typedef __attribute__((ext_vector_type(4))) float  f32x4;

// async global->LDS, 16B per lane; lds dest = wave-uniform base + lane*16
__device__ __forceinline__ void gld_lds16(const __bf16* g, __bf16* l)
{
    __builtin_amdgcn_global_load_lds(
        (const __attribute__((address_space(1))) void*)g,
        (__attribute__((address_space(3))) void*)l, 16, 0, 0);
}

// inline-asm ds_read_b128: invisible to SIInsertWaitcnts' LDS-DMA alias
// tracking, so the compiler cannot insert vmcnt drains before it.
// Completion is enforced by OUR "s_waitcnt lgkmcnt(0)" + sched_barrier.
__device__ __forceinline__ bf16x8 ds_read_b128a(const __bf16* p)
{
    bf16x8 r;
    unsigned a = (unsigned)(size_t)(const __attribute__((address_space(3))) __bf16*)p;
    asm volatile("ds_read_b128 %0, %1" : "=&v"(r) : "v"(a));
    return r;
}

// ---------------------------------------------------------------- cast fp32 -> bf16 (vectorized)
__global__ __launch_bounds__(256) void cast_bf16_kernel(
    const float* __restrict__ in, __bf16* __restrict__ out, int n4)
{
    int i = blockIdx.x * 256 + threadIdx.x;
    if (i < n4) {
        f32x4 v = ((const f32x4*)in)[i];
        bf16x4 o;
        o[0] = (__bf16)v[0]; o[1] = (__bf16)v[1];
        o[2] = (__bf16)v[2]; o[3] = (__bf16)v[3];
        ((bf16x4*)out)[i] = o;
    }
}

// ---------------------------------------------------------------- transpose + cast: in (R x C) f32 -> out (C x R) bf16
__global__ __launch_bounds__(256) void transpose_cast_kernel(
    const float* __restrict__ in, __bf16* __restrict__ out, int R, int C)
{
    __shared__ float tile[32][33];
    int c0 = blockIdx.x * 32, r0 = blockIdx.y * 32;
    int tx = threadIdx.x;   // 0..31
    int ty = threadIdx.y;   // 0..7
#pragma unroll
    for (int j = 0; j < 32; j += 8)
        tile[ty + j][tx] = in[(size_t)(r0 + ty + j) * C + c0 + tx];
    __syncthreads();
#pragma unroll
    for (int j = 0; j < 32; j += 8)
        out[(size_t)(c0 + ty + j) * R + r0 + tx] = (__bf16)tile[tx][ty + j];
}

// ---------------------------------------------------------------- 256x256 8-phase bf16 GEMM (m201 structure)
// C(MxN, f32) = A(MxK) * Bt(NxK)^T + bias(N).
// 512 thr = 8 waves (2M x 4N); per-wave 128x64 out; BK=64 as 2 kk-halves.
// LDS: 2 dbuf x {A_kk0,A_kk1,B_kk0,B_kk1} x 16KB = 128KB.
// Swizzle: physical 16B block = logical ^ ((row>>1)&3) (involution),
// applied via pre-swizzled global SOURCE on staging + swizzled ds_read.
// Stage stream item idx: j=idx>>2 (K-tile), sel=idx&3 in order
// [B_kk0, B_kk1, A_kk0, A_kk1]; during K-tile k we stage items 4k+7..4k+10
// (= A_kk1(k+1), B_kk0(k+2), B_kk1(k+2), A_kk0(k+2)) which are always
// dead regions: B dead after phase0, A_kk0 after phase1, A_kk1 other buf.
// vmcnt(6) once per K-tile (3 half-tiles in flight), vmcnt(0) only to drain.
// Fragment LDS reads are inline asm (see ds_read_b128a) so the ONLY vmem
// waits in the loop are the counted ones below.

#define SB()    __builtin_amdgcn_sched_barrier(0)
#define BAR()   __builtin_amdgcn_s_barrier()
#define LGKM0() asm volatile("s_waitcnt lgkmcnt(0)" ::: "memory")

#define LOAD_A(MH, KK)                                                          \
    _Pragma("unroll")                                                           \
    for (int m = 0; m < 4; ++m)                                                 \
        afr[m] = ds_read_b128a(&lds[buf][KK][(wm * 128 + ((MH)*4 + m) * 16 + col) * 32 + pbE]);

#define MFMA_QUAD(MH, KK)                                                       \
    __builtin_amdgcn_s_setprio(1);                                              \
    _Pragma("unroll")                                                           \
    for (int m = 0; m < 4; ++m) {                                               \
        _Pragma("unroll")                                                       \
        for (int n = 0; n < 4; ++n)                                             \
            acc[(MH)*4 + m][n] = __builtin_amdgcn_mfma_f32_16x16x32_bf16(       \
                afr[m], bfr[KK][n], acc[(MH)*4 + m][n], 0, 0, 0);               \
    }                                                                           \
    __builtin_amdgcn_s_setprio(0);

__global__ __launch_bounds__(512, 2) void gemm256_kernel(
    const __bf16* __restrict__ A, const __bf16* __restrict__ Bt,
    const float* __restrict__ bias, float* __restrict__ C,
    int M, int N, int K)
{
    // region: 0=A_kk0, 1=A_kk1, 2=B_kk0, 3=B_kk1 (each 256 rows x 32 cols)
    __shared__ __bf16 lds[2][4][8192];

    const int tid  = threadIdx.x;
    const int lane = tid & 63;
    const int wave = tid >> 6;          // 0..7
    const int wm   = wave >> 2;         // 0..1
    const int wn   = wave & 3;          // 0..3
    const int col  = lane & 15;
    const int quad = lane >> 4;
    const int pbE  = (quad ^ ((lane >> 1) & 3)) * 8;   // swizzled block, elems
    const int bm   = blockIdx.y * 256;
    const int bn   = blockIdx.x * 256;
    const int nk   = K >> 6;
    const int nitems = nk << 2;

    // staging: per wave-instruction 64 lanes x 16B = 16 rows x 64B.
    // lane covers physical block (lane&3) of row (lane>>2); its logical
    // (= global) block is (lane&3) ^ ((lane>>3)&3)  [same involution].
    const int sR = wave * 32 + (lane >> 2);
    const int sb = ((lane & 3) ^ ((lane >> 3) & 3)) * 8;
    const __bf16* gA = A  + (size_t)(bm + sR) * K + sb;
    const __bf16* gB = Bt + (size_t)(bn + sR) * K + sb;

    f32x4 acc[8][4];
#pragma unroll
    for (int m = 0; m < 8; ++m)
#pragma unroll
        for (int n = 0; n < 4; ++n)
#pragma unroll
            for (int r = 0; r < 4; ++r) acc[m][n][r] = 0.f;

    auto stage = [&](int idx) {
        if (idx >= nitems) return;
        const int j   = idx >> 2;
        const int sel = idx & 3;
        const int reg = sel ^ 2;        // 0,1 -> B regions 2,3 ; 2,3 -> A 0,1
        const __bf16* g = (sel & 2) ? gA : gB;
        const size_t koff = (size_t)j * 64 + (size_t)(sel & 1) * 32;
        __bf16* l = &lds[j & 1][reg][wave * 1024];
        gld_lds16(g + koff, l);
        gld_lds16(g + koff + (size_t)16 * K, l + 512);
    };

    // prologue: items 0..6 (K-tile0 complete + 3 of K-tile1)
    stage(0); stage(1); stage(2); stage(3);
    asm volatile("s_waitcnt vmcnt(4)" ::: "memory");
    stage(4); stage(5); stage(6);
    asm volatile("s_waitcnt vmcnt(6)" ::: "memory");
    BAR();
    SB();

    for (int k = 0; k < nk; ++k) {
        const int buf = k & 1;
        bf16x8 bfr[2][4];
        bf16x8 afr[4];

        // -------- phase 0: all B (8) + A m0-3 kk0 (4); MFMA m0-3 kk0
#pragma unroll
        for (int kk = 0; kk < 2; ++kk)
#pragma unroll
            for (int n = 0; n < 4; ++n)
                bfr[kk][n] = ds_read_b128a(&lds[buf][2 + kk][(wn * 64 + n * 16 + col) * 32 + pbE]);
        LOAD_A(0, 0)
        stage(4 * k + 7);
        SB(); BAR(); LGKM0(); SB();
        MFMA_QUAD(0, 0)
        SB(); BAR(); SB();

        // -------- phase 1: A m4-7 kk0; MFMA m4-7 kk0
        LOAD_A(1, 0)
        stage(4 * k + 8);
        SB(); BAR(); LGKM0(); SB();
        MFMA_QUAD(1, 0)
        SB(); BAR(); SB();

        // -------- phase 2: A m0-3 kk1; MFMA m0-3 kk1
        LOAD_A(0, 1)
        stage(4 * k + 9);
        SB(); BAR(); LGKM0(); SB();
        MFMA_QUAD(0, 1)
        SB(); BAR(); SB();

        // -------- phase 3: A m4-7 kk1; MFMA m4-7 kk1; counted vmcnt
        LOAD_A(1, 1)
        stage(4 * k + 10);
        SB(); BAR(); LGKM0(); SB();
        MFMA_QUAD(1, 1)
        SB();
        if (k < nk - 2) asm volatile("s_waitcnt vmcnt(6)" ::: "memory");
        else            asm volatile("s_waitcnt vmcnt(0)" ::: "memory");
        BAR();
        SB();
    }

    // epilogue: D row = quad*4+r, col = lane&15 within each 16x16 frag
#pragma unroll
    for (int m = 0; m < 8; ++m) {
#pragma unroll
        for (int n = 0; n < 4; ++n) {
            const int r0 = bm + wm * 128 + m * 16 + quad * 4;
            const int c0 = bn + wn * 64 + n * 16 + col;
            const float bv = bias[c0];
#pragma unroll
            for (int r = 0; r < 4; ++r)
                C[(size_t)(r0 + r) * N + c0] = acc[m][n][r] + bv;
        }
    }
}

// ---------------------------------------------------------------- RoPE + cache scatter + bf16 q/k/v
__global__ __launch_bounds__(256) void rope_scatter_kernel(
    const float* __restrict__ qkv, const float* __restrict__ cosb,
    const float* __restrict__ sinb, const int* __restrict__ slots,
    __bf16* __restrict__ q16, __bf16* __restrict__ k16, __bf16* __restrict__ v16,
    float* __restrict__ kcache, float* __restrict__ vcache)
{
    const int t = blockIdx.x;
    const int tid = threadIdx.x;
    const float* row = qkv + (size_t)t * NQKV_;
    const float* cr = cosb + (size_t)t * 64;
    const float* sr = sinb + (size_t)t * 64;
    const int slot = slots[t];

#pragma unroll
    for (int i = 0; i < 8; ++i) {
        int p = tid + 256 * i;       // 0..2047
        int h = p >> 6;
        int d = p & 63;
        float x1 = row[h * 128 + d];
        float x2 = row[h * 128 + 64 + d];
        float c = cr[d], s = sr[d];
        q16[(size_t)t * HID_ + h * 128 + d]      = (__bf16)(x1 * c - x2 * s);
        q16[(size_t)t * HID_ + h * 128 + 64 + d] = (__bf16)(x2 * c + x1 * s);
    }
    if (tid < 64) {
        int d = tid;
        float x1 = row[HID_ + d];
        float x2 = row[HID_ + 64 + d];
        float c = cr[d], s = sr[d];
        float o1 = x1 * c - x2 * s;
        float o2 = x2 * c + x1 * s;
        kcache[(size_t)slot * D_ + d]      = o1;
        kcache[(size_t)slot * D_ + 64 + d] = o2;
        k16[(size_t)t * D_ + d]      = (__bf16)o1;
        k16[(size_t)t * D_ + 64 + d] = (__bf16)o2;
    }
    if (tid < 128) {
        float v = row[HID_ + 128 + tid];
        vcache[(size_t)slot * D_ + tid] = v;
        v16[(size_t)t * D_ + tid] = (__bf16)v;
    }
}

// ---------------------------------------------------------------- flash MQA attention (bf16 MFMA)
// grid (4, H, B): block processes q-tiles qt=blockIdx.x AND 7-blockIdx.x
// (uniform 18 k-steps/block -> no causal tail imbalance).
__global__ __launch_bounds__(256) void attn_kernel(
    const __bf16* __restrict__ Q, const __bf16* __restrict__ Kc,
    const __bf16* __restrict__ Vc, __bf16* __restrict__ O)
{
    __shared__ __bf16 sK[64][136];      // k-tile (s x d) row-major
    __shared__ __bf16 sVt[128][72];     // V transposed (d x s)
    __shared__ __bf16 sP[4][32][72];    // per-wave P round-trip (C-layout -> A-layout)

    const int h  = blockIdx.y;
    const int b  = blockIdx.z;
    const int tid = threadIdx.x, lane = tid & 63, wave = tid >> 6;
    const int col = lane & 15, quad = lane >> 4;
    const int tbase = b * S_;
    const float scale = 0.08838834764831845f; // 1/sqrt(128)

    for (int half = 0; half < 2; ++half) {
        const int qt = half ? (7 - blockIdx.x) : blockIdx.x;
        const int qb = qt * 128;

        bf16x8 aq[2][4];
#pragma unroll
        for (int mt = 0; mt < 2; ++mt)
#pragma unroll
            for (int ks = 0; ks < 4; ++ks)
                aq[mt][ks] = *(const bf16x8*)&Q[(size_t)(tbase + qb + wave * 32 + mt * 16 + col) * HID_
                                                + h * 128 + ks * 32 + quad * 8];

        f32x4 o[2][8];
#pragma unroll
        for (int mt = 0; mt < 2; ++mt)
#pragma unroll
            for (int nd = 0; nd < 8; ++nd)
#pragma unroll
                for (int r = 0; r < 4; ++r) o[mt][nd][r] = 0.f;
        float m_i[2][4], l_i[2][4];
#pragma unroll
        for (int mt = 0; mt < 2; ++mt)
#pragma unroll
            for (int r = 0; r < 4; ++r) { m_i[mt][r] = -3.0e38f; l_i[mt][r] = 0.f; }

        const int ntiles = qt * 2 + 2;
        for (int kt = 0; kt < ntiles; ++kt) {
            const int kb = kt * 64;
            __syncthreads();
            // stage K (64 x 128) row-major, coalesced vector loads
#pragma unroll
            for (int i = 0; i < 4; ++i) {
                int c = tid + i * 256;           // 0..1023
                int srow = c >> 4;               // 0..63
                int d0 = (c & 15) * 8;
                *(uint4*)&sK[srow][d0] = *(const uint4*)&Kc[(size_t)(tbase + kb + srow) * D_ + d0];
            }
            // stage V transposed: srow = c&63 so consecutive lanes write
            // consecutive sVt elements (2-way bank alias = free; was 16-way)
#pragma unroll
            for (int i = 0; i < 4; ++i) {
                int c = tid + i * 256;
                int srow = c & 63;
                int d0 = (c >> 6) * 8;
                bf16x8 v = *(const bf16x8*)&Vc[(size_t)(tbase + kb + srow) * D_ + d0];
#pragma unroll
                for (int j = 0; j < 8; ++j) sVt[d0 + j][srow] = v[j];
            }
            __syncthreads();

            // QK^T: per wave 32x64 scores
            f32x4 sc[2][4];
#pragma unroll
            for (int mt = 0; mt < 2; ++mt)
#pragma unroll
                for (int nt = 0; nt < 4; ++nt)
#pragma unroll
                    for (int r = 0; r < 4; ++r) sc[mt][nt][r] = 0.f;
#pragma unroll
            for (int ks = 0; ks < 4; ++ks) {
                bf16x8 bk[4];
#pragma unroll
                for (int nt = 0; nt < 4; ++nt)
                    bk[nt] = *(const bf16x8*)&sK[nt * 16 + col][ks * 32 + quad * 8];
#pragma unroll
                for (int mt = 0; mt < 2; ++mt)
#pragma unroll
                    for (int nt = 0; nt < 4; ++nt)
                        sc[mt][nt] = __builtin_amdgcn_mfma_f32_16x16x32_bf16(
                            aq[mt][ks], bk[nt], sc[mt][nt], 0, 0, 0);
            }

            // scale + causal mask + online softmax
#pragma unroll
            for (int mt = 0; mt < 2; ++mt) {
#pragma unroll
                for (int r = 0; r < 4; ++r) {
                    int qrow = qb + wave * 32 + mt * 16 + quad * 4 + r;
#pragma unroll
                    for (int nt = 0; nt < 4; ++nt) {
                        float v = sc[mt][nt][r] * scale;
                        int kcol = kb + nt * 16 + col;
                        sc[mt][nt][r] = (kcol > qrow) ? -3.0e38f : v;
                    }
                    float mx = sc[mt][0][r];
#pragma unroll
                    for (int nt = 1; nt < 4; ++nt) mx = fmaxf(mx, sc[mt][nt][r]);
#pragma unroll
                    for (int x = 1; x < 16; x <<= 1) mx = fmaxf(mx, __shfl_xor(mx, x, 64));
                    float mnew = fmaxf(m_i[mt][r], mx);
                    float alpha = __expf(m_i[mt][r] - mnew);
                    m_i[mt][r] = mnew;
                    float rs = 0.f;
#pragma unroll
                    for (int nt = 0; nt < 4; ++nt) {
                        float p = __expf(sc[mt][nt][r] - mnew);
                        sc[mt][nt][r] = p;
                        rs += p;
                    }
#pragma unroll
                    for (int x = 1; x < 16; x <<= 1) rs += __shfl_xor(rs, x, 64);
                    l_i[mt][r] = l_i[mt][r] * alpha + rs;
#pragma unroll
                    for (int nd = 0; nd < 8; ++nd) o[mt][nd][r] *= alpha;
                }
            }

            // P: C-layout regs -> per-wave LDS; same-wave RAW needs NO barrier
#pragma unroll
            for (int mt = 0; mt < 2; ++mt)
#pragma unroll
                for (int nt = 0; nt < 4; ++nt)
#pragma unroll
                    for (int r = 0; r < 4; ++r)
                        sP[wave][mt * 16 + quad * 4 + r][nt * 16 + col] = (__bf16)sc[mt][nt][r];

            // PV: O(32 x 128) += P(32 x 64) * V(64 x 128)
#pragma unroll
            for (int ks2 = 0; ks2 < 2; ++ks2) {
                bf16x8 ap[2];
#pragma unroll
                for (int mt = 0; mt < 2; ++mt)
                    ap[mt] = *(const bf16x8*)&sP[wave][mt * 16 + col][ks2 * 32 + quad * 8];
#pragma unroll
                for (int nd = 0; nd < 8; ++nd) {
                    bf16x8 bv = *(const bf16x8*)&sVt[nd * 16 + col][ks2 * 32 + quad * 8];
#pragma unroll
                    for (int mt = 0; mt < 2; ++mt)
                        o[mt][nd] = __builtin_amdgcn_mfma_f32_16x16x32_bf16(
                            ap[mt], bv, o[mt][nd], 0, 0, 0);
                }
            }
        }

        // epilogue: O /= l, write bf16 (T, HID)
#pragma unroll
        for (int mt = 0; mt < 2; ++mt) {
#pragma unroll
            for (int r = 0; r < 4; ++r) {
                int t = tbase + qb + wave * 32 + mt * 16 + quad * 4 + r;
                float inv_l = 1.f / l_i[mt][r];
#pragma unroll
                for (int nd = 0; nd < 8; ++nd)
                    O[(size_t)t * HID_ + h * 128 + nd * 16 + col] = (__bf16)(o[mt][nd][r] * inv_l);
            }
        }
    }
}

// ---------------------------------------------------------------- launch
extern "C" void kernel_launch(void* const* d_in, const int* in_sizes, int n_in,
                              void* d_out, int out_size, void* d_ws, size_t ws_size,
                              hipStream_t stream)
{
    const float* hidden  = (const float*)d_in[0];
    const float* cosb    = (const float*)d_in[1];
    const float* sinb    = (const float*)d_in[2];
    const float* kc_in   = (const float*)d_in[3];
    const float* vc_in   = (const float*)d_in[4];
    const float* qkv_w   = (const float*)d_in[5];
    const float* qkv_b   = (const float*)d_in[6];
    const float* dense_w = (const float*)d_in[7];
    const float* dense_b = (const float*)d_in[8];
    const int*   slots   = (const int*)d_in[9];

    float* out    = (float*)d_out;
    float* kc_out = out + (size_t)T_ * HID_;
    float* vc_out = kc_out + (size_t)NSLOTS_ * D_;

    char* ws = (char*)d_ws;
    __bf16* A16 = (__bf16*)(ws);
    __bf16* W1T = (__bf16*)(ws + 33554432);
    float*  QKV = (float*)(ws + 69206016);
    __bf16* W2T = (__bf16*)(ws + 69206016);   // alias: qkv f32 dead after rope
    __bf16* Q16 = (__bf16*)d_out;             // staged in out region (dead before GEMM2)
    __bf16* K16 = (__bf16*)((char*)d_out + 33554432);
    __bf16* V16 = (__bf16*)((char*)d_out + 34603008);

    cast_bf16_kernel<<<(T_ * HID_ / 4 + 255) / 256, 256, 0, stream>>>(hidden, A16, T_ * HID_ / 4);
    transpose_cast_kernel<<<dim3(NQKV_ / 32, HID_ / 32), dim3(32, 8), 0, stream>>>(qkv_w, W1T, HID_, NQKV_);
    gemm256_kernel<<<dim3(NQKV_ / 256, T_ / 256), 512, 0, stream>>>(A16, W1T, qkv_b, QKV, T_, NQKV_, HID_);
    hipMemcpyAsync(kc_out, kc_in, (size_t)NSLOTS_ * D_ * 4, hipMemcpyDeviceToDevice, stream);
    hipMemcpyAsync(vc_out, vc_in, (size_t)NSLOTS_ * D_ * 4, hipMemcpyDeviceToDevice, stream);
    rope_scatter_kernel<<<T_, 256, 0, stream>>>(QKV, cosb, sinb, slots, Q16, K16, V16, kc_out, vc_out);
    transpose_cast_kernel<<<dim3(HID_ / 32, HID_ / 32), dim3(32, 8), 0, stream>>>(dense_w, W2T, HID_, HID_);
    attn_kernel<<<dim3(4, H_, B_), 256, 0, stream>>>(Q16, K16, V16, A16);
    gemm256_kernel<<<dim3(HID_ / 256, T_ / 256), 512, 0, stream>>>(A16, W2T, dense_b, out, T_, HID_, HID_);
}

// Round 3
// 734.073 us; speedup vs baseline: 1.1213x; 1.0005x over previous
//
#include <hip/hip_runtime.h>

// ---------------------------------------------------------------- constants
#define H_   32
#define D_   128
#define HID_ 4096
#define B_   4
#define S_   1024
#define T_   4096
#define NSLOTS_ 16384
#define NQKV_ 4352   // HID + 2*D

typedef __attribute__((ext_vector_type(8))) __bf16 bf16x8;
typedef __attribute__((ext_vector_type(4))) __bf16 bf16x4;
typedef __attribute__((ext_vector_type(4))) float  f32x4;

// async global->LDS, 16B per lane; lds dest = wave-uniform base + lane*16
__device__ __forceinline__ void gld_lds16(const __bf16* g, __bf16* l)
{
    __builtin_amdgcn_global_load_lds(
        (const __attribute__((address_space(1))) void*)g,
        (__attribute__((address_space(3))) void*)l, 16, 0, 0);
}

// inline-asm ds_read_b128: invisible to the compiler's waitcnt pass, so
// OUR counted lgkmcnt waits are the only DS synchronization in the loop.
__device__ __forceinline__ bf16x8 ds_read_b128a(const __bf16* p)
{
    bf16x8 r;
    unsigned a = (unsigned)(size_t)(const __attribute__((address_space(3))) __bf16*)p;
    asm volatile("ds_read_b128 %0, %1" : "=&v"(r) : "v"(a));
    return r;
}

// ---------------------------------------------------------------- cast fp32 -> bf16 (vectorized)
__global__ __launch_bounds__(256) void cast_bf16_kernel(
    const float* __restrict__ in, __bf16* __restrict__ out, int n4)
{
    int i = blockIdx.x * 256 + threadIdx.x;
    if (i < n4) {
        f32x4 v = ((const f32x4*)in)[i];
        bf16x4 o;
        o[0] = (__bf16)v[0]; o[1] = (__bf16)v[1];
        o[2] = (__bf16)v[2]; o[3] = (__bf16)v[3];
        ((bf16x4*)out)[i] = o;
    }
}

// ---------------------------------------------------------------- transpose + cast: in (R x C) f32 -> out (C x R) bf16
__global__ __launch_bounds__(256) void transpose_cast_kernel(
    const float* __restrict__ in, __bf16* __restrict__ out, int R, int C)
{
    __shared__ float tile[32][33];
    int c0 = blockIdx.x * 32, r0 = blockIdx.y * 32;
    int tx = threadIdx.x;   // 0..31
    int ty = threadIdx.y;   // 0..7
#pragma unroll
    for (int j = 0; j < 32; j += 8)
        tile[ty + j][tx] = in[(size_t)(r0 + ty + j) * C + c0 + tx];
    __syncthreads();
#pragma unroll
    for (int j = 0; j < 32; j += 8)
        out[(size_t)(c0 + ty + j) * R + r0 + tx] = (__bf16)tile[tx][ty + j];
}

// ---------------------------------------------------------------- 256x256 4-phase PIPELINED bf16 GEMM
// C(MxN, f32) = A(MxK) * Bt(NxK)^T + bias(N).
// 512 thr = 8 waves (2M x 4N); per-wave 128x64 out; BK=64 as 2 kk-halves.
// LDS: 2 dbuf x {A_kk0,A_kk1,B_kk0,B_kk1} x 16KB = 128KB. Swizzled (see r1).
//
// Pipelined fragment reads: phase p issues ds_reads for phase p+1's MFMA;
// counted lgkmcnt(N_issued_this_phase) before MFMA keeps this phase's reads
// in flight UNDER the MFMA (ds_read || MFMA overlap — the T3 lever).
//   P0: rd A(1,kk0)+B(kk1)[8]; MFMA(a_cur x b0)  [MH0,kk0]; vmcnt(8); BAR
//   P1: rd A(0,kk1)[4];        MFMA(a_nxt x b0)  [MH1,kk0];           BAR
//   P2: rd A(1,kk1)[4];        MFMA(a_cur x b1)  [MH0,kk1]; vmcnt(6); BAR
//   P3: rd next A(0,kk0)+B(kk0)[8]; MFMA(a_nxt x b1) [MH1,kk1];       BAR
// Stage stream: item 4j+{0,1,2,3} = {B_kk0,B_kk1,A_kk0,A_kk1}(tile j);
// during tile k phases 0..3 stage items 4k+7..4k+10. Derived waits:
//   endP0 vmcnt(8) -> complete through item 4k+3 (A_kk1(k), read P1/P2)
//   endP2 vmcnt(6) -> complete through item 4(k+1)+2 (B/A_kk0(k+1), read P3)
// vmcnt is per-wave => each wait sits immediately before a barrier.
// Last 2 tiles: stage stream ends, counted arithmetic breaks -> vmcnt(0).
// WAR (stage overwriting regions): every stage target's last readers finish
// >=1 end-barrier before the stage issues (verified per region).

#define SB()    __builtin_amdgcn_sched_barrier(0)
#define BAR()   __builtin_amdgcn_s_barrier()

#define MFMA4(MH, AFR, BFR)                                                     \
    __builtin_amdgcn_s_setprio(1);                                              \
    _Pragma("unroll")                                                           \
    for (int m = 0; m < 4; ++m) {                                               \
        _Pragma("unroll")                                                       \
        for (int n = 0; n < 4; ++n)                                             \
            acc[(MH)*4 + m][n] = __builtin_amdgcn_mfma_f32_16x16x32_bf16(       \
                AFR[m], BFR[n], acc[(MH)*4 + m][n], 0, 0, 0);                   \
    }                                                                           \
    __builtin_amdgcn_s_setprio(0);

__global__ __launch_bounds__(512, 2) void gemm256_kernel(
    const __bf16* __restrict__ A, const __bf16* __restrict__ Bt,
    const float* __restrict__ bias, float* __restrict__ C,
    int M, int N, int K)
{
    // region: 0=A_kk0, 1=A_kk1, 2=B_kk0, 3=B_kk1 (each 256 rows x 32 cols)
    __shared__ __bf16 lds[2][4][8192];

    const int tid  = threadIdx.x;
    const int lane = tid & 63;
    const int wave = tid >> 6;          // 0..7
    const int wm   = wave >> 2;         // 0..1
    const int wn   = wave & 3;          // 0..3
    const int col  = lane & 15;
    const int quad = lane >> 4;
    const int pbE  = (quad ^ ((lane >> 1) & 3)) * 8;   // swizzled block, elems
    const int bm   = blockIdx.y * 256;
    const int bn   = blockIdx.x * 256;
    const int nk   = K >> 6;
    const int nitems = nk << 2;

    // staging: lane covers physical block (lane&3) of row (lane>>2); its
    // logical (= global) block is (lane&3) ^ ((lane>>3)&3) [same involution].
    const int sR = wave * 32 + (lane >> 2);
    const int sb = ((lane & 3) ^ ((lane >> 3) & 3)) * 8;
    const __bf16* gA = A  + (size_t)(bm + sR) * K + sb;
    const __bf16* gB = Bt + (size_t)(bn + sR) * K + sb;

    f32x4 acc[8][4];
#pragma unroll
    for (int m = 0; m < 8; ++m)
#pragma unroll
        for (int n = 0; n < 4; ++n)
#pragma unroll
            for (int r = 0; r < 4; ++r) acc[m][n][r] = 0.f;

    auto stage = [&](int idx) {
        if (idx >= nitems) return;
        const int j   = idx >> 2;
        const int sel = idx & 3;
        const int reg = sel ^ 2;        // 0,1 -> B regions 2,3 ; 2,3 -> A 0,1
        const __bf16* g = (sel & 2) ? gA : gB;
        const size_t koff = (size_t)j * 64 + (size_t)(sel & 1) * 32;
        __bf16* l = &lds[j & 1][reg][wave * 1024];
        gld_lds16(g + koff, l);
        gld_lds16(g + koff + (size_t)16 * K, l + 512);
    };

    auto rdA = [&](int bf, int kk, int mh, bf16x8* dst) {
#pragma unroll
        for (int m = 0; m < 4; ++m)
            dst[m] = ds_read_b128a(&lds[bf][kk][(wm * 128 + (mh * 4 + m) * 16 + col) * 32 + pbE]);
    };
    auto rdB = [&](int bf, int kk, bf16x8* dst) {
#pragma unroll
        for (int n = 0; n < 4; ++n)
            dst[n] = ds_read_b128a(&lds[bf][2 + kk][(wn * 64 + n * 16 + col) * 32 + pbE]);
    };

    bf16x8 a_cur[4], a_nxt[4], b0[4], b1[4];

    // prologue: items 0..6 (tile0 full + B_kk0,B_kk1,A_kk0 of tile1)
    stage(0); stage(1); stage(2); stage(3);
    stage(4); stage(5); stage(6);                      // 14 instrs in flight
    asm volatile("s_waitcnt vmcnt(8)" ::: "memory");   // items 0,1,2 landed
    BAR();
    SB();
    rdA(0, 0, 0, a_cur);    // A(0,kk0)(0)
    rdB(0, 0, b0);          // B(kk0)(0)   [8 reads pending]
    SB();

    for (int k = 0; k < nk; ++k) {
        const int buf = k & 1;

        // ---- P0: rd a_nxt=A(1,kk0), b1=B(kk1) [8]; MFMA(a_cur,b0) MH0
        rdA(buf, 0, 1, a_nxt);
        rdB(buf, 1, b1);
        stage(4 * k + 7);
        SB();
        asm volatile("s_waitcnt lgkmcnt(8)" ::: "memory"); SB();
        MFMA4(0, a_cur, b0)
        SB();
        if (k < nk - 2) asm volatile("s_waitcnt vmcnt(8)" ::: "memory");
        else            asm volatile("s_waitcnt vmcnt(0)" ::: "memory");
        BAR(); SB();

        // ---- P1: rd a_cur=A(0,kk1) [4]; MFMA(a_nxt,b0) MH1
        rdA(buf, 1, 0, a_cur);
        stage(4 * k + 8);
        SB();
        asm volatile("s_waitcnt lgkmcnt(4)" ::: "memory"); SB();
        MFMA4(1, a_nxt, b0)
        SB(); BAR(); SB();

        // ---- P2: rd a_nxt=A(1,kk1) [4]; MFMA(a_cur,b1) MH0
        rdA(buf, 1, 1, a_nxt);
        stage(4 * k + 9);
        SB();
        asm volatile("s_waitcnt lgkmcnt(4)" ::: "memory"); SB();
        MFMA4(0, a_cur, b1)
        SB();
        if (k < nk - 2) asm volatile("s_waitcnt vmcnt(6)" ::: "memory");
        else            asm volatile("s_waitcnt vmcnt(0)" ::: "memory");
        BAR(); SB();

        // ---- P3: rd next-tile a_cur=A(0,kk0), b0=B(kk0) [8]; MFMA(a_nxt,b1) MH1
        rdA(buf ^ 1, 0, 0, a_cur);
        rdB(buf ^ 1, 0, b0);
        stage(4 * k + 10);
        SB();
        asm volatile("s_waitcnt lgkmcnt(8)" ::: "memory"); SB();
        MFMA4(1, a_nxt, b1)
        SB(); BAR(); SB();
    }

    // epilogue: D row = quad*4+r, col = lane&15 within each 16x16 frag
#pragma unroll
    for (int m = 0; m < 8; ++m) {
#pragma unroll
        for (int n = 0; n < 4; ++n) {
            const int r0 = bm + wm * 128 + m * 16 + quad * 4;
            const int c0 = bn + wn * 64 + n * 16 + col;
            const float bv = bias[c0];
#pragma unroll
            for (int r = 0; r < 4; ++r)
                C[(size_t)(r0 + r) * N + c0] = acc[m][n][r] + bv;
        }
    }
}

// ---------------------------------------------------------------- RoPE + cache scatter + bf16 q/k/v
__global__ __launch_bounds__(256) void rope_scatter_kernel(
    const float* __restrict__ qkv, const float* __restrict__ cosb,
    const float* __restrict__ sinb, const int* __restrict__ slots,
    __bf16* __restrict__ q16, __bf16* __restrict__ k16, __bf16* __restrict__ v16,
    float* __restrict__ kcache, float* __restrict__ vcache)
{
    const int t = blockIdx.x;
    const int tid = threadIdx.x;
    const float* row = qkv + (size_t)t * NQKV_;
    const float* cr = cosb + (size_t)t * 64;
    const float* sr = sinb + (size_t)t * 64;
    const int slot = slots[t];

#pragma unroll
    for (int i = 0; i < 8; ++i) {
        int p = tid + 256 * i;       // 0..2047
        int h = p >> 6;
        int d = p & 63;
        float x1 = row[h * 128 + d];
        float x2 = row[h * 128 + 64 + d];
        float c = cr[d], s = sr[d];
        q16[(size_t)t * HID_ + h * 128 + d]      = (__bf16)(x1 * c - x2 * s);
        q16[(size_t)t * HID_ + h * 128 + 64 + d] = (__bf16)(x2 * c + x1 * s);
    }
    if (tid < 64) {
        int d = tid;
        float x1 = row[HID_ + d];
        float x2 = row[HID_ + 64 + d];
        float c = cr[d], s = sr[d];
        float o1 = x1 * c - x2 * s;
        float o2 = x2 * c + x1 * s;
        kcache[(size_t)slot * D_ + d]      = o1;
        kcache[(size_t)slot * D_ + 64 + d] = o2;
        k16[(size_t)t * D_ + d]      = (__bf16)o1;
        k16[(size_t)t * D_ + 64 + d] = (__bf16)o2;
    }
    if (tid < 128) {
        float v = row[HID_ + 128 + tid];
        vcache[(size_t)slot * D_ + tid] = v;
        v16[(size_t)t * D_ + tid] = (__bf16)v;
    }
}

// ---------------------------------------------------------------- flash MQA attention (bf16 MFMA)
// grid (4, H, B): block processes q-tiles qt=blockIdx.x AND 7-blockIdx.x
// (uniform 18 k-steps/block -> no causal tail imbalance).
__global__ __launch_bounds__(256) void attn_kernel(
    const __bf16* __restrict__ Q, const __bf16* __restrict__ Kc,
    const __bf16* __restrict__ Vc, __bf16* __restrict__ O)
{
    __shared__ __bf16 sK[64][136];      // k-tile (s x d) row-major
    __shared__ __bf16 sVt[128][72];     // V transposed (d x s)
    __shared__ __bf16 sP[4][32][72];    // per-wave P round-trip (C-layout -> A-layout)

    const int h  = blockIdx.y;
    const int b  = blockIdx.z;
    const int tid = threadIdx.x, lane = tid & 63, wave = tid >> 6;
    const int col = lane & 15, quad = lane >> 4;
    const int tbase = b * S_;
    const float scale = 0.08838834764831845f; // 1/sqrt(128)

    for (int half = 0; half < 2; ++half) {
        const int qt = half ? (7 - blockIdx.x) : blockIdx.x;
        const int qb = qt * 128;

        bf16x8 aq[2][4];
#pragma unroll
        for (int mt = 0; mt < 2; ++mt)
#pragma unroll
            for (int ks = 0; ks < 4; ++ks)
                aq[mt][ks] = *(const bf16x8*)&Q[(size_t)(tbase + qb + wave * 32 + mt * 16 + col) * HID_
                                                + h * 128 + ks * 32 + quad * 8];

        f32x4 o[2][8];
#pragma unroll
        for (int mt = 0; mt < 2; ++mt)
#pragma unroll
            for (int nd = 0; nd < 8; ++nd)
#pragma unroll
                for (int r = 0; r < 4; ++r) o[mt][nd][r] = 0.f;
        float m_i[2][4], l_i[2][4];
#pragma unroll
        for (int mt = 0; mt < 2; ++mt)
#pragma unroll
            for (int r = 0; r < 4; ++r) { m_i[mt][r] = -3.0e38f; l_i[mt][r] = 0.f; }

        const int ntiles = qt * 2 + 2;
        for (int kt = 0; kt < ntiles; ++kt) {
            const int kb = kt * 64;
            __syncthreads();
            // stage K (64 x 128) row-major, coalesced vector loads
#pragma unroll
            for (int i = 0; i < 4; ++i) {
                int c = tid + i * 256;           // 0..1023
                int srow = c >> 4;               // 0..63
                int d0 = (c & 15) * 8;
                *(uint4*)&sK[srow][d0] = *(const uint4*)&Kc[(size_t)(tbase + kb + srow) * D_ + d0];
            }
            // stage V transposed: srow = c&63 so consecutive lanes write
            // consecutive sVt elements (2-way bank alias = free; was 16-way)
#pragma unroll
            for (int i = 0; i < 4; ++i) {
                int c = tid + i * 256;
                int srow = c & 63;
                int d0 = (c >> 6) * 8;
                bf16x8 v = *(const bf16x8*)&Vc[(size_t)(tbase + kb + srow) * D_ + d0];
#pragma unroll
                for (int j = 0; j < 8; ++j) sVt[d0 + j][srow] = v[j];
            }
            __syncthreads();

            // QK^T: per wave 32x64 scores
            f32x4 sc[2][4];
#pragma unroll
            for (int mt = 0; mt < 2; ++mt)
#pragma unroll
                for (int nt = 0; nt < 4; ++nt)
#pragma unroll
                    for (int r = 0; r < 4; ++r) sc[mt][nt][r] = 0.f;
#pragma unroll
            for (int ks = 0; ks < 4; ++ks) {
                bf16x8 bk[4];
#pragma unroll
                for (int nt = 0; nt < 4; ++nt)
                    bk[nt] = *(const bf16x8*)&sK[nt * 16 + col][ks * 32 + quad * 8];
#pragma unroll
                for (int mt = 0; mt < 2; ++mt)
#pragma unroll
                    for (int nt = 0; nt < 4; ++nt)
                        sc[mt][nt] = __builtin_amdgcn_mfma_f32_16x16x32_bf16(
                            aq[mt][ks], bk[nt], sc[mt][nt], 0, 0, 0);
            }

            // scale + causal mask + online softmax
#pragma unroll
            for (int mt = 0; mt < 2; ++mt) {
#pragma unroll
                for (int r = 0; r < 4; ++r) {
                    int qrow = qb + wave * 32 + mt * 16 + quad * 4 + r;
#pragma unroll
                    for (int nt = 0; nt < 4; ++nt) {
                        float v = sc[mt][nt][r] * scale;
                        int kcol = kb + nt * 16 + col;
                        sc[mt][nt][r] = (kcol > qrow) ? -3.0e38f : v;
                    }
                    float mx = sc[mt][0][r];
#pragma unroll
                    for (int nt = 1; nt < 4; ++nt) mx = fmaxf(mx, sc[mt][nt][r]);
#pragma unroll
                    for (int x = 1; x < 16; x <<= 1) mx = fmaxf(mx, __shfl_xor(mx, x, 64));
                    float mnew = fmaxf(m_i[mt][r], mx);
                    float alpha = __expf(m_i[mt][r] - mnew);
                    m_i[mt][r] = mnew;
                    float rs = 0.f;
#pragma unroll
                    for (int nt = 0; nt < 4; ++nt) {
                        float p = __expf(sc[mt][nt][r] - mnew);
                        sc[mt][nt][r] = p;
                        rs += p;
                    }
#pragma unroll
                    for (int x = 1; x < 16; x <<= 1) rs += __shfl_xor(rs, x, 64);
                    l_i[mt][r] = l_i[mt][r] * alpha + rs;
#pragma unroll
                    for (int nd = 0; nd < 8; ++nd) o[mt][nd][r] *= alpha;
                }
            }

            // P: C-layout regs -> per-wave LDS; same-wave RAW needs NO barrier
#pragma unroll
            for (int mt = 0; mt < 2; ++mt)
#pragma unroll
                for (int nt = 0; nt < 4; ++nt)
#pragma unroll
                    for (int r = 0; r < 4; ++r)
                        sP[wave][mt * 16 + quad * 4 + r][nt * 16 + col] = (__bf16)sc[mt][nt][r];

            // PV: O(32 x 128) += P(32 x 64) * V(64 x 128)
#pragma unroll
            for (int ks2 = 0; ks2 < 2; ++ks2) {
                bf16x8 ap[2];
#pragma unroll
                for (int mt = 0; mt < 2; ++mt)
                    ap[mt] = *(const bf16x8*)&sP[wave][mt * 16 + col][ks2 * 32 + quad * 8];
#pragma unroll
                for (int nd = 0; nd < 8; ++nd) {
                    bf16x8 bv = *(const bf16x8*)&sVt[nd * 16 + col][ks2 * 32 + quad * 8];
#pragma unroll
                    for (int mt = 0; mt < 2; ++mt)
                        o[mt][nd] = __builtin_amdgcn_mfma_f32_16x16x32_bf16(
                            ap[mt], bv, o[mt][nd], 0, 0, 0);
                }
            }
        }

        // epilogue: O /= l, write bf16 (T, HID)
#pragma unroll
        for (int mt = 0; mt < 2; ++mt) {
#pragma unroll
            for (int r = 0; r < 4; ++r) {
                int t = tbase + qb + wave * 32 + mt * 16 + quad * 4 + r;
                float inv_l = 1.f / l_i[mt][r];
#pragma unroll
                for (int nd = 0; nd < 8; ++nd)
                    O[(size_t)t * HID_ + h * 128 + nd * 16 + col] = (__bf16)(o[mt][nd][r] * inv_l);
            }
        }
    }
}

// ---------------------------------------------------------------- launch
extern "C" void kernel_launch(void* const* d_in, const int* in_sizes, int n_in,
                              void* d_out, int out_size, void* d_ws, size_t ws_size,
                              hipStream_t stream)
{
    const float* hidden  = (const float*)d_in[0];
    const float* cosb    = (const float*)d_in[1];
    const float* sinb    = (const float*)d_in[2];
    const float* kc_in   = (const float*)d_in[3];
    const float* vc_in   = (const float*)d_in[4];
    const float* qkv_w   = (const float*)d_in[5];
    const float* qkv_b   = (const float*)d_in[6];
    const float* dense_w = (const float*)d_in[7];
    const float* dense_b = (const float*)d_in[8];
    const int*   slots   = (const int*)d_in[9];

    float* out    = (float*)d_out;
    float* kc_out = out + (size_t)T_ * HID_;
    float* vc_out = kc_out + (size_t)NSLOTS_ * D_;

    char* ws = (char*)d_ws;
    __bf16* A16 = (__bf16*)(ws);
    __bf16* W1T = (__bf16*)(ws + 33554432);
    float*  QKV = (float*)(ws + 69206016);
    __bf16* W2T = (__bf16*)(ws + 69206016);   // alias: qkv f32 dead after rope
    __bf16* Q16 = (__bf16*)d_out;             // staged in out region (dead before GEMM2)
    __bf16* K16 = (__bf16*)((char*)d_out + 33554432);
    __bf16* V16 = (__bf16*)((char*)d_out + 34603008);

    cast_bf16_kernel<<<(T_ * HID_ / 4 + 255) / 256, 256, 0, stream>>>(hidden, A16, T_ * HID_ / 4);
    transpose_cast_kernel<<<dim3(NQKV_ / 32, HID_ / 32), dim3(32, 8), 0, stream>>>(qkv_w, W1T, HID_, NQKV_);
    gemm256_kernel<<<dim3(NQKV_ / 256, T_ / 256), 512, 0, stream>>>(A16, W1T, qkv_b, QKV, T_, NQKV_, HID_);
    hipMemcpyAsync(kc_out, kc_in, (size_t)NSLOTS_ * D_ * 4, hipMemcpyDeviceToDevice, stream);
    hipMemcpyAsync(vc_out, vc_in, (size_t)NSLOTS_ * D_ * 4, hipMemcpyDeviceToDevice, stream);
    rope_scatter_kernel<<<T_, 256, 0, stream>>>(QKV, cosb, sinb, slots, Q16, K16, V16, kc_out, vc_out);
    transpose_cast_kernel<<<dim3(HID_ / 32, HID_ / 32), dim3(32, 8), 0, stream>>>(dense_w, W2T, HID_, HID_);
    attn_kernel<<<dim3(4, H_, B_), 256, 0, stream>>>(Q16, K16, V16, A16);
    gemm256_kernel<<<dim3(HID_ / 256, T_ / 256), 512, 0, stream>>>(A16, W2T, dense_b, out, T_, HID_, HID_);
}